// Round 1
// baseline (146.606 us; speedup 1.0000x reference)
//
#include <hip/hip_runtime.h>
#include <math.h>

#define GRID_G 60
#define GRID_GG 3600
#define BPB 8  // boxes per block

__device__ __forceinline__ float wredsum(float v){
  #pragma unroll
  for (int m = 32; m; m >>= 1) v += __shfl_xor(v, m, 64);
  return v;
}
__device__ __forceinline__ float wredmax(float v){
  #pragma unroll
  for (int m = 32; m; m >>= 1) v = fmaxf(v, __shfl_xor(v, m, 64));
  return v;
}
__device__ __forceinline__ float wredmin(float v){
  #pragma unroll
  for (int m = 32; m; m >>= 1) v = fminf(v, __shfl_xor(v, m, 64));
  return v;
}
__device__ __forceinline__ float sigmoidf_(float x){ return 1.0f / (1.0f + expf(-x)); }

__global__ __launch_bounds__(256) void tracker_kernel(
    const float* __restrict__ mv,        // (2,60,60)
    const float* __restrict__ boxes,     // (N,4)
    const float* __restrict__ W_stats, const float* __restrict__ b_stats,
    const float* __restrict__ g_stats, const float* __restrict__ be_stats,
    const float* __restrict__ W_b1,  const float* __restrict__ b_b1,
    const float* __restrict__ g_b1,  const float* __restrict__ be_b1,
    const float* __restrict__ W_b2,  const float* __restrict__ b_b2,
    const float* __restrict__ g_b2,  const float* __restrict__ be_b2,
    const float* __restrict__ W_ih,  const float* __restrict__ b_ih,
    const float* __restrict__ b_hh,
    const float* __restrict__ W_p1,  const float* __restrict__ b_p1,
    const float* __restrict__ W_p2,  const float* __restrict__ b_p2,
    const float* __restrict__ W_s1,  const float* __restrict__ b_s1,
    const float* __restrict__ W_s2,  const float* __restrict__ b_s2,
    const float* __restrict__ W_c1,  const float* __restrict__ b_c1,
    const float* __restrict__ W_c2,  const float* __restrict__ b_c2,
    float* __restrict__ out, int N)
{
  __shared__ __align__(16) float x_lds[BPB][96];    // concat [mv_feat(64) | box_feat(32)]
  __shared__ __align__(16) float h_lds[BPB][128];   // LSTM hidden
  __shared__ float u_lds[3*BPB][65];                // head hidden, +1 pad vs 64 (bank conflicts)
  __shared__ float res_lds[BPB][5];

  const int tid  = threadIdx.x;
  const int lane = tid & 63;
  const int wave = tid >> 6;
  const int base = blockIdx.x * BPB;

  // ================= Phase 1: stats + small MLPs (one wave per box, 2 boxes/wave)
  for (int bb = 0; bb < 2; ++bb) {
    const int b  = wave * 2 + bb;
    int gb = base + b; if (gb >= N) gb = N - 1;      // clamp: safe dup work for tail
    const float4 bx = ((const float4*)boxes)[gb];
    const float bn0 = fminf(fmaxf(bx.x * (1.0f/960.0f), 0.f), 1.f);
    const float bn1 = fminf(fmaxf(bx.y * (1.0f/960.0f), 0.f), 1.f);
    const float bn2 = fminf(fmaxf(bx.z * (1.0f/960.0f), 0.f), 1.f);
    const float bn3 = fminf(fmaxf(bx.w * (1.0f/960.0f), 0.f), 1.f);

    int x1 = (int)floorf(bn0 * 60.f); x1 = min(max(x1, 0), 59);
    int y1 = (int)floorf(bn1 * 60.f); y1 = min(max(y1, 0), 59);
    int x2 = (int)ceilf (bn2 * 60.f); x2 = min(max(x2, x1 + 1), 60);
    int y2 = (int)ceilf (bn3 * 60.f); y2 = min(max(y2, y1 + 1), 60);
    const int w = x2 - x1, hh = y2 - y1;
    const int cnt = w * hh;

    float s0=0.f, s1=0.f, q0=0.f, q1=0.f;
    float hi0=-1e30f, hi1=-1e30f, lo0=1e30f, lo1=1e30f;
    for (int c = lane; c < cnt; c += 64) {
      const int yy = y1 + c / w;
      const int xx = x1 + c % w;
      const int idx = yy * GRID_G + xx;
      const float m0 = mv[idx];
      const float m1 = mv[GRID_GG + idx];
      s0 += m0; q0 += m0*m0; hi0 = fmaxf(hi0, m0); lo0 = fminf(lo0, m0);
      s1 += m1; q1 += m1*m1; hi1 = fmaxf(hi1, m1); lo1 = fminf(lo1, m1);
    }
    s0 = wredsum(s0); q0 = wredsum(q0); hi0 = wredmax(hi0); lo0 = wredmin(lo0);
    s1 = wredsum(s1); q1 = wredsum(q1); hi1 = wredmax(hi1); lo1 = wredmin(lo1);
    const float inv = 1.0f / (float)cnt;
    float st[6];
    st[0] = s0 * inv;
    st[1] = s1 * inv;
    st[2] = sqrtf(fmaxf(q0 * inv - st[0]*st[0], 0.f));
    st[3] = sqrtf(fmaxf(q1 * inv - st[1]*st[1], 0.f));
    st[4] = hi0 - lo0;
    st[5] = hi1 - lo1;

    // mv_feat: 64 outputs, one per lane; LN over 64; relu
    {
      const float* Wr = W_stats + lane * 6;
      float v = b_stats[lane];
      #pragma unroll
      for (int k = 0; k < 6; ++k) v += st[k] * Wr[k];
      const float mu  = wredsum(v) * (1.0f/64.0f);
      const float var = wredsum(v*v) * (1.0f/64.0f) - mu*mu;
      const float y = (v - mu) * rsqrtf(var + 1e-5f) * g_stats[lane] + be_stats[lane];
      x_lds[b][lane] = fmaxf(y, 0.f);
    }

    // h1: 32 outputs (lanes 0-31 canonical, upper lanes duplicate); LN over 32; relu
    const int l32 = lane & 31;
    float h1v;
    {
      const float* Wr = W_b1 + l32 * 4;
      const float v = b_b1[l32] + bn0*Wr[0] + bn1*Wr[1] + bn2*Wr[2] + bn3*Wr[3];
      const float cv  = (lane < 32) ? v     : 0.f;
      const float cq  = (lane < 32) ? v*v   : 0.f;
      const float mu  = wredsum(cv) * (1.0f/32.0f);
      const float var = wredsum(cq) * (1.0f/32.0f) - mu*mu;
      h1v = fmaxf((v - mu) * rsqrtf(var + 1e-5f) * g_b1[l32] + be_b1[l32], 0.f);
    }

    // box_feat: dot over 32 h1 values (via shuffle broadcast); LN over 32; relu
    {
      const float* Wr = W_b2 + l32 * 32;
      float v = b_b2[l32];
      #pragma unroll
      for (int k = 0; k < 32; ++k) v += __shfl(h1v, k, 64) * Wr[k];
      const float cv  = (lane < 32) ? v   : 0.f;
      const float cq  = (lane < 32) ? v*v : 0.f;
      const float mu  = wredsum(cv) * (1.0f/32.0f);
      const float var = wredsum(cq) * (1.0f/32.0f) - mu*mu;
      const float y = fmaxf((v - mu) * rsqrtf(var + 1e-5f) * g_b2[l32] + be_b2[l32], 0.f);
      if (lane < 32) x_lds[b][64 + l32] = y;
    }
  }
  __syncthreads();

  // ================= Phase 2: LSTM gates (h0=c0=0 => skip W_hh and f-gate)
  {
    const int j  = tid & 127;          // hidden index 0..127
    const int b0 = (tid >> 7) * 4;     // boxes 0-3 or 4-7
    float ai[4] = {0,0,0,0}, ag[4] = {0,0,0,0}, ao[4] = {0,0,0,0};
    const float4* Wi = (const float4*)(W_ih + (size_t)(j      ) * 96);
    const float4* Wg = (const float4*)(W_ih + (size_t)(j + 256) * 96);
    const float4* Wo = (const float4*)(W_ih + (size_t)(j + 384) * 96);
    #pragma unroll 4
    for (int kk = 0; kk < 24; ++kk) {
      const float4 wi = Wi[kk], wg = Wg[kk], wo = Wo[kk];
      #pragma unroll
      for (int b = 0; b < 4; ++b) {
        const float4 xv = *(const float4*)(&x_lds[b0 + b][kk * 4]);
        ai[b] = fmaf(wi.x,xv.x, fmaf(wi.y,xv.y, fmaf(wi.z,xv.z, fmaf(wi.w,xv.w, ai[b]))));
        ag[b] = fmaf(wg.x,xv.x, fmaf(wg.y,xv.y, fmaf(wg.z,xv.z, fmaf(wg.w,xv.w, ag[b]))));
        ao[b] = fmaf(wo.x,xv.x, fmaf(wo.y,xv.y, fmaf(wo.z,xv.z, fmaf(wo.w,xv.w, ao[b]))));
      }
    }
    const float bi = b_ih[j      ] + b_hh[j      ];
    const float bg = b_ih[j + 256] + b_hh[j + 256];
    const float bo = b_ih[j + 384] + b_hh[j + 384];
    #pragma unroll
    for (int b = 0; b < 4; ++b) {
      const float c = sigmoidf_(ai[b] + bi) * tanhf(ag[b] + bg);
      const float h = sigmoidf_(ao[b] + bo) * tanhf(c);
      h_lds[b0 + b][j] = h;
    }
  }
  __syncthreads();

  // ================= Phase 3: head hidden layers (3 heads x 64 units = 192 threads)
  if (tid < 192) {
    const int head = tid >> 6;
    const int l    = tid & 63;
    const float* W1 = (head == 0) ? W_p1 : (head == 1) ? W_s1 : W_c1;
    const float* B1 = (head == 0) ? b_p1 : (head == 1) ? b_s1 : b_c1;
    float acc[BPB] = {0,0,0,0,0,0,0,0};
    const float4* Wr = (const float4*)(W1 + (size_t)l * 128);
    #pragma unroll 4
    for (int kk = 0; kk < 32; ++kk) {
      const float4 w = Wr[kk];
      #pragma unroll
      for (int b = 0; b < BPB; ++b) {
        const float4 hv = *(const float4*)(&h_lds[b][kk * 4]);
        acc[b] = fmaf(w.x,hv.x, fmaf(w.y,hv.y, fmaf(w.z,hv.z, fmaf(w.w,hv.w, acc[b]))));
      }
    }
    const float bias = B1[l];
    #pragma unroll
    for (int b = 0; b < BPB; ++b)
      u_lds[head * BPB + b][l] = fmaxf(acc[b] + bias, 0.f);
  }
  __syncthreads();

  // ================= Phase 4: head output layers (8 boxes x 5 outputs = 40 threads)
  if (tid < BPB * 5) {
    const int b = tid / 5, o = tid % 5;
    const int head = (o < 2) ? 0 : (o < 4) ? 1 : 2;
    const float* W2; float bias;
    if      (o == 0) { W2 = W_p2;      bias = b_p2[0]; }
    else if (o == 1) { W2 = W_p2 + 64; bias = b_p2[1]; }
    else if (o == 2) { W2 = W_s2;      bias = b_s2[0]; }
    else if (o == 3) { W2 = W_s2 + 64; bias = b_s2[1]; }
    else             { W2 = W_c2;      bias = b_c2[0]; }
    const float* ur = u_lds[head * BPB + b];
    float acc = bias;
    #pragma unroll 8
    for (int k = 0; k < 64; ++k) acc += ur[k] * W2[k];
    res_lds[b][o] = acc;
  }
  __syncthreads();

  // ================= Phase 5: box decode + write
  if (tid < BPB) {
    const int gb = base + tid;
    if (gb < N) {
      const float4 bx = ((const float4*)boxes)[gb];
      const float cx = (bx.x + bx.z) * 0.5f;
      const float cy = (bx.y + bx.w) * 0.5f;
      const float w  = bx.z - bx.x;
      const float hh = bx.w - bx.y;
      const float ncx = cx + res_lds[tid][0];
      const float ncy = cy + res_lds[tid][1];
      const float nw  = w  * expf(res_lds[tid][2]);
      const float nh  = hh * expf(res_lds[tid][3]);
      const float cf  = 1.0f / (1.0f + expf(-res_lds[tid][4]));
      float* op = out + (size_t)gb * 5;
      op[0] = ncx - nw * 0.5f;
      op[1] = ncy - nh * 0.5f;
      op[2] = ncx + nw * 0.5f;
      op[3] = ncy + nh * 0.5f;
      op[4] = cf;
    }
  }
}

extern "C" void kernel_launch(void* const* d_in, const int* in_sizes, int n_in,
                              void* d_out, int out_size, void* d_ws, size_t ws_size,
                              hipStream_t stream) {
  (void)n_in; (void)out_size; (void)d_ws; (void)ws_size;
  const float* mv       = (const float*)d_in[0];
  const float* boxes    = (const float*)d_in[1];
  const float* W_stats  = (const float*)d_in[2];
  const float* b_stats  = (const float*)d_in[3];
  const float* g_stats  = (const float*)d_in[4];
  const float* be_stats = (const float*)d_in[5];
  const float* W_b1     = (const float*)d_in[6];
  const float* b_b1     = (const float*)d_in[7];
  const float* g_b1     = (const float*)d_in[8];
  const float* be_b1    = (const float*)d_in[9];
  const float* W_b2     = (const float*)d_in[10];
  const float* b_b2     = (const float*)d_in[11];
  const float* g_b2     = (const float*)d_in[12];
  const float* be_b2    = (const float*)d_in[13];
  const float* W_ih     = (const float*)d_in[14];
  // d_in[15] = W_hh: unused (h0 == 0)
  const float* b_ih     = (const float*)d_in[16];
  const float* b_hh     = (const float*)d_in[17];
  const float* W_p1     = (const float*)d_in[18];
  const float* b_p1     = (const float*)d_in[19];
  const float* W_p2     = (const float*)d_in[20];
  const float* b_p2     = (const float*)d_in[21];
  const float* W_s1     = (const float*)d_in[22];
  const float* b_s1     = (const float*)d_in[23];
  const float* W_s2     = (const float*)d_in[24];
  const float* b_s2     = (const float*)d_in[25];
  const float* W_c1     = (const float*)d_in[26];
  const float* b_c1     = (const float*)d_in[27];
  const float* W_c2     = (const float*)d_in[28];
  const float* b_c2     = (const float*)d_in[29];

  const int N = in_sizes[1] / 4;
  const int grid = (N + BPB - 1) / BPB;
  tracker_kernel<<<grid, 256, 0, stream>>>(
      mv, boxes,
      W_stats, b_stats, g_stats, be_stats,
      W_b1, b_b1, g_b1, be_b1,
      W_b2, b_b2, g_b2, be_b2,
      W_ih, b_ih, b_hh,
      W_p1, b_p1, W_p2, b_p2,
      W_s1, b_s1, W_s2, b_s2,
      W_c1, b_c1, W_c2, b_c2,
      (float*)d_out, N);
}